// Round 4
// baseline (555.603 us; speedup 1.0000x reference)
//
#include <hip/hip_runtime.h>
#include <hip/hip_cooperative_groups.h>
#include <hip/hip_bf16.h>
#include <math.h>

namespace cg = cooperative_groups;

// Problem constants (fixed by the reference file)
#define N     8192
#define F_IN  256
#define F_OUT 64
#define ALPHA 0.2f
#define NBLK  1024          // 4 blocks/CU on 256 CUs -> cooperative-safe
#define RPB   8             // rows per block (N / NBLK)

// ---------------------------------------------------------------------------
// Fused GAT: one cooperative kernel, three phases separated by grid syncs.
//  B: Wh = h@W, wh1/wh2 row scores, per-block colsum partials
//  C: colsum reduction (blocks 0..63)
//  D: per-row sparse attention aggregation + ELU epilogue
//      out[u,f] = elu((sum_e w_e*Wh[col_e,f] + colsum[f]) / (sum_e w_e + N))
//      w_e = expm1(leakyrelu(wh1[u] + wh2[col]))   (non-edges contribute
//      exp(0)=1, folded into colsum / +N analytically)
// ---------------------------------------------------------------------------
__global__ __launch_bounds__(256, 4) void gat_fused_kernel(
    const float* __restrict__ h,       // [N, 256]
    const float* __restrict__ adj,     // [N, N]
    const float* __restrict__ W,       // [256, 64]
    const float* __restrict__ a,       // [128]
    float* __restrict__ Wh,            // [N, 64]        (ws)
    float* __restrict__ wh1,           // [N]            (ws)
    float* __restrict__ wh2,           // [N]            (ws)
    float* __restrict__ colpart,       // [NBLK, 64]     (ws)
    float* __restrict__ colsum,        // [64]           (ws)
    float* __restrict__ out)           // [N, 64]
{
    __shared__ float s_h[RPB][F_IN];   // 8 KiB
    __shared__ float s_cp[256];        // 1 KiB

    const int tid = threadIdx.x;
    const int wv  = tid >> 6;          // wave 0..3
    const int ln  = tid & 63;          // lane -> output feature
    const int rowbase = blockIdx.x * RPB;

    // ================= Phase B: Wh rows (2 rows per wave) =================
    {
        const float4* hsrc = (const float4*)(h + (size_t)rowbase * F_IN);
        float4* hdst = (float4*)&s_h[0][0];
        hdst[tid]       = hsrc[tid];         // 512 float4 total, coalesced
        hdst[tid + 256] = hsrc[tid + 256];
    }
    __syncthreads();

    const int r0 = wv * 2;
    float acc0 = 0.f, acc1 = 0.f;
#pragma unroll 8
    for (int k2 = 0; k2 < F_IN / 2; ++k2) {
        const int k = k2 * 2;
        const float wk0 = W[(k + 0) * F_OUT + ln];   // coalesced, L2-hot
        const float wk1 = W[(k + 1) * F_OUT + ln];
        const float2 h0 = *(const float2*)&s_h[r0 + 0][k];  // LDS broadcast
        const float2 h1 = *(const float2*)&s_h[r0 + 1][k];
        acc0 += h0.x * wk0 + h0.y * wk1;
        acc1 += h1.x * wk0 + h1.y * wk1;
    }

    {
        const float a2 = a[ln];          // dest term coeff
        const float a1 = a[F_OUT + ln];  // source term coeff
        const int u0 = rowbase + r0;
        Wh[(size_t)u0 * F_OUT + ln]       = acc0;
        Wh[(size_t)(u0 + 1) * F_OUT + ln] = acc1;
        float p10 = acc0 * a1, p20 = acc0 * a2;
        float p11 = acc1 * a1, p21 = acc1 * a2;
#pragma unroll
        for (int off = 32; off > 0; off >>= 1) {
            p10 += __shfl_down(p10, off);
            p20 += __shfl_down(p20, off);
            p11 += __shfl_down(p11, off);
            p21 += __shfl_down(p21, off);
        }
        if (ln == 0) {
            wh1[u0] = p10;  wh2[u0] = p20;
            wh1[u0 + 1] = p11;  wh2[u0 + 1] = p21;
        }
    }

    // per-block colsum partial
    s_cp[tid] = acc0 + acc1;
    __syncthreads();
    if (tid < 64) {
        colpart[(size_t)blockIdx.x * 64 + tid] =
            s_cp[tid] + s_cp[tid + 64] + s_cp[tid + 128] + s_cp[tid + 192];
    }

    cg::this_grid().sync();

    // ================= Phase C: colsum (blocks 0..63) =====================
    if (blockIdx.x < 64) {
        const int f = blockIdx.x;
        float s = 0.f;
        for (int b = tid; b < NBLK; b += 256) s += colpart[(size_t)b * 64 + f];
        s_cp[tid] = s;
        __syncthreads();
        if (tid < 128) s_cp[tid] += s_cp[tid + 128];
        __syncthreads();
        if (tid < 64) {
            float x = s_cp[tid] + s_cp[tid + 64];
#pragma unroll
            for (int off = 32; off > 0; off >>= 1) x += __shfl_down(x, off);
            if (tid == 0) colsum[f] = x;
        }
    }

    cg::this_grid().sync();

    // ================= Phase D: sparse aggregation (2 rows per wave) ======
    const float cs = colsum[ln];
#pragma unroll
    for (int r = 0; r < 2; ++r) {
        const int u = rowbase + wv + 4 * r;
        const float wh1u = wh1[u];
        const float* __restrict__ arow = adj + (size_t)u * N;

        float acc  = 0.f;     // feature `ln` accumulator
        float sumw = 0.f;     // uniform across lanes

        for (int it = 0; it < 16; ++it) {
            const int cbase = it * 512;
            const float4* p = (const float4*)(arow + cbase + ln * 8);
            const float4 v0 = p[0];
            const float4 v1 = p[1];
            const float vals[8] = {v0.x, v0.y, v0.z, v0.w,
                                   v1.x, v1.y, v1.z, v1.w};
#pragma unroll
            for (int j = 0; j < 8; ++j) {
                unsigned long long m = __ballot(vals[j] != 0.f);
                while (m) {                         // wave-uniform walk
                    const int l = __ffsll((long long)m) - 1;
                    m &= m - 1;
                    const int col = cbase + l * 8 + j;
                    float e = wh1u + wh2[col];      // uniform broadcast load
                    e = (e >= 0.f) ? e : ALPHA * e; // LeakyReLU
                    const float w = expm1f(e);
                    sumw += w;
                    acc += w * Wh[((size_t)col << 6) + ln];  // 256B row read
                }
            }
        }

        const float val = (acc + cs) / (sumw + (float)N);
        out[((size_t)u << 6) + ln] = (val > 0.f) ? val : expm1f(val);
    }
}

// ---------------------------------------------------------------------------
// Launch
// ---------------------------------------------------------------------------
extern "C" void kernel_launch(void* const* d_in, const int* in_sizes, int n_in,
                              void* d_out, int out_size, void* d_ws, size_t ws_size,
                              hipStream_t stream) {
    const float* h   = (const float*)d_in[0];   // [8192, 256]
    const float* adj = (const float*)d_in[1];   // [8192, 8192]
    const float* W   = (const float*)d_in[2];   // [256, 64]
    const float* a   = (const float*)d_in[3];   // [128, 1]
    float* out = (float*)d_out;                 // [8192, 64]

    // Workspace layout (floats)
    float* ws      = (float*)d_ws;
    float* Wh      = ws;                        // 524288
    float* wh1     = Wh + (size_t)N * F_OUT;    // 8192
    float* wh2     = wh1 + N;                   // 8192
    float* colpart = wh2 + N;                   // 1024*64
    float* colsum  = colpart + (size_t)NBLK * 64; // 64

    void* args[] = {
        (void*)&h, (void*)&adj, (void*)&W, (void*)&a,
        (void*)&Wh, (void*)&wh1, (void*)&wh2,
        (void*)&colpart, (void*)&colsum, (void*)&out
    };
    hipLaunchCooperativeKernel((const void*)gat_fused_kernel,
                               dim3(NBLK), dim3(256), args, 0, stream);
}

// Round 6
// 459.333 us; speedup vs baseline: 1.2096x; 1.2096x over previous
//
#include <hip/hip_runtime.h>
#include <hip/hip_bf16.h>
#include <math.h>

// Problem constants (fixed by the reference file)
#define N     8192
#define F_IN  256
#define F_OUT 64
#define ALPHA 0.2f
#define MAXE  192      // per-row edge capacity (mean deg ~33, binomial max ~60)

// ---------------------------------------------------------------------------
// Kernel B: Wh = h @ W; wh1[u] = Wh[u,:]@a[64:128]; wh2[u] = Wh[u,:]@a[0:64];
// per-block colsum partials; also zeroes cnt[]. 512 blocks x 256 (16 rows/blk).
// ---------------------------------------------------------------------------
__global__ __launch_bounds__(256) void gat_wh_kernel(
    const float* __restrict__ h,      // [N, 256]
    const float* __restrict__ W,      // [256, 64]
    const float* __restrict__ a,      // [128]
    float* __restrict__ Wh,           // [N, 64]
    float* __restrict__ wh1,          // [N]
    float* __restrict__ wh2,          // [N]
    float* __restrict__ colpart,      // [512, 64]
    int*   __restrict__ cnt)          // [N]  (zeroed here)
{
    __shared__ float s_h[16][F_IN];   // 16 KiB = 1024 float4
    __shared__ float s_cp[256];

    const int tid = threadIdx.x;
    const int wv  = tid >> 6;
    const int ln  = tid & 63;
    const int rowbase = blockIdx.x * 16;

    // zero the edge counters (first 8192 threads of the grid)
    const int gtid = blockIdx.x * 256 + tid;
    if (gtid < N) cnt[gtid] = 0;

    // Stage 16 h rows = 1024 float4; 4 per thread, coalesced.
    {
        const float4* hsrc = (const float4*)(h + (size_t)rowbase * F_IN);
        float4* hdst = (float4*)&s_h[0][0];
#pragma unroll
        for (int i = 0; i < 4; ++i) hdst[tid + 256 * i] = hsrc[tid + 256 * i];
    }
    __syncthreads();

    const int r0 = wv * 4;            // 4 rows per wave
    float acc[4] = {0.f, 0.f, 0.f, 0.f};

#pragma unroll 4
    for (int k2 = 0; k2 < F_IN / 2; ++k2) {
        const int k = k2 * 2;
        const float wk0 = W[(k + 0) * F_OUT + ln];   // coalesced, L2-hot
        const float wk1 = W[(k + 1) * F_OUT + ln];
#pragma unroll
        for (int r = 0; r < 4; ++r) {
            const float2 hv = *(const float2*)&s_h[r0 + r][k];  // LDS broadcast
            acc[r] += hv.x * wk0 + hv.y * wk1;
        }
    }

    const float a2 = a[ln];           // dest term coeff
    const float a1 = a[F_OUT + ln];   // source term coeff
    float colacc = 0.f;
#pragma unroll
    for (int r = 0; r < 4; ++r) {
        const int u = rowbase + r0 + r;
        Wh[(size_t)u * F_OUT + ln] = acc[r];
        colacc += acc[r];
        float p1 = acc[r] * a1;
        float p2 = acc[r] * a2;
#pragma unroll
        for (int off = 32; off > 0; off >>= 1) {
            p1 += __shfl_down(p1, off);
            p2 += __shfl_down(p2, off);
        }
        if (ln == 0) { wh1[u] = p1; wh2[u] = p2; }
    }

    s_cp[tid] = colacc;
    __syncthreads();
    if (tid < 64) {
        colpart[(size_t)blockIdx.x * 64 + tid] =
            s_cp[tid] + s_cp[tid + 64] + s_cp[tid + 128] + s_cp[tid + 192];
    }
}

// ---------------------------------------------------------------------------
// Kernel C: colsum[f] = sum_b colpart[b][f].  1 block x 256 threads.
// ---------------------------------------------------------------------------
__global__ __launch_bounds__(256) void gat_colsum_kernel(
    const float* __restrict__ colpart,   // [512, 64]
    float* __restrict__ colsum)          // [64]
{
    __shared__ float r[256];
    const int tid = threadIdx.x;
    const int f = tid & 63;
    const int g = tid >> 6;
    float s = 0.f;
    for (int b = g; b < 512; b += 4) s += colpart[(size_t)b * 64 + f];
    r[tid] = s;
    __syncthreads();
    if (tid < 64) colsum[f] = r[f] + r[f + 64] + r[f + 128] + r[f + 192];
}

// ---------------------------------------------------------------------------
// Kernel E: edge extraction — PURE STREAM, no dependent loads.
// One wave per row; lane reads 8 consecutive floats/chunk (2x float4,
// coalesced 2KiB/wave/iter). Nonzeros append their column index to the
// row's compact list via atomicAdd (rare: ~0.5 edges per lane-iter).
// ---------------------------------------------------------------------------
__global__ __launch_bounds__(256) void gat_edge_kernel(
    const float* __restrict__ adj,     // [N, N]
    int* __restrict__ cnt,             // [N]
    int* __restrict__ cols)            // [N, MAXE]
{
    const int tid = threadIdx.x;
    const int ln  = tid & 63;
    const int wv  = tid >> 6;
    const int u   = blockIdx.x * 4 + wv;

    const float* __restrict__ arow = adj + (size_t)u * N;
    int* __restrict__ rowcols = cols + (size_t)u * MAXE;

#pragma unroll 2
    for (int it = 0; it < 16; ++it) {
        const int base = it * 512 + ln * 8;
        const float4 v0 = *(const float4*)(arow + base);
        const float4 v1 = *(const float4*)(arow + base + 4);
        const float vals[8] = {v0.x, v0.y, v0.z, v0.w, v1.x, v1.y, v1.z, v1.w};
#pragma unroll
        for (int j = 0; j < 8; ++j) {
            if (vals[j] != 0.f) {
                const int pos = atomicAdd(&cnt[u], 1);
                if (pos < MAXE) rowcols[pos] = base + j;
            }
        }
    }
}

// ---------------------------------------------------------------------------
// Kernel F: gather over compact edge lists + epilogue. One wave per row.
// Lanes load up to 64 edge cols in parallel, compute w in parallel
// (wh2 is 32KB -> L1-hot), then broadcast (col,w) via register shfl and
// gather coalesced 256B Wh rows (Wh = 2MB -> L2-resident).
// ---------------------------------------------------------------------------
__global__ __launch_bounds__(256) void gat_gather_kernel(
    const int*   __restrict__ cnt,     // [N]
    const int*   __restrict__ cols,    // [N, MAXE]
    const float* __restrict__ Wh,      // [N, 64]
    const float* __restrict__ wh1,     // [N]
    const float* __restrict__ wh2,     // [N]
    const float* __restrict__ colsum,  // [64]
    float* __restrict__ out)           // [N, 64]
{
    const int tid = threadIdx.x;
    const int ln  = tid & 63;
    const int wv  = tid >> 6;
    const int u   = blockIdx.x * 4 + wv;

    const int n = min(cnt[u], MAXE);
    const float wh1u = wh1[u];
    const int* __restrict__ rowcols = cols + (size_t)u * MAXE;

    float acc  = 0.f;      // feature `ln`
    float sumw = 0.f;      // uniform across lanes

    for (int b0 = 0; b0 < n; b0 += 64) {
        const int m = min(64, n - b0);
        // parallel per-lane precompute of this batch's (col, w)
        int   col_own = 0;
        float w_own   = 0.f;
        if (ln < m) {
            col_own = rowcols[b0 + ln];            // coalesced
            float e = wh1u + wh2[col_own];         // L1-hot gather
            e = (e >= 0.f) ? e : ALPHA * e;        // LeakyReLU
            w_own = expm1f(e);                     // exp(e)-1
        }
        // wave-uniform walk: register broadcasts, independent Wh loads
        for (int l = 0; l < m; ++l) {
            const int   col = __shfl(col_own, l);
            const float w   = __shfl(w_own, l);
            sumw += w;
            acc += w * Wh[((size_t)col << 6) + ln];  // coalesced 256B row
        }
    }

    const float val = (acc + colsum[ln]) / (sumw + (float)N);
    out[((size_t)u << 6) + ln] = (val > 0.f) ? val : expm1f(val);
}

// ---------------------------------------------------------------------------
// Launch
// ---------------------------------------------------------------------------
extern "C" void kernel_launch(void* const* d_in, const int* in_sizes, int n_in,
                              void* d_out, int out_size, void* d_ws, size_t ws_size,
                              hipStream_t stream) {
    const float* h   = (const float*)d_in[0];   // [8192, 256]
    const float* adj = (const float*)d_in[1];   // [8192, 8192]
    const float* W   = (const float*)d_in[2];   // [256, 64]
    const float* a   = (const float*)d_in[3];   // [128, 1]
    float* out = (float*)d_out;                 // [8192, 64]

    // Workspace layout
    float* ws      = (float*)d_ws;
    float* Wh      = ws;                        // 524288 floats
    float* wh1     = Wh + (size_t)N * F_OUT;    // 8192
    float* wh2     = wh1 + N;                   // 8192
    float* colpart = wh2 + N;                   // 512*64
    float* colsum  = colpart + 512 * 64;        // 64
    int*   cnt     = (int*)(colsum + 64);       // 8192 ints
    int*   cols    = cnt + N;                   // 8192*MAXE ints

    gat_wh_kernel<<<N / 16, 256, 0, stream>>>(h, W, a, Wh, wh1, wh2, colpart, cnt);
    gat_edge_kernel<<<N / 4, 256, 0, stream>>>(adj, cnt, cols);
    gat_colsum_kernel<<<1, 256, 0, stream>>>(colpart, colsum);
    gat_gather_kernel<<<N / 4, 256, 0, stream>>>(cnt, cols, Wh, wh1, wh2, colsum, out);
}